// Round 5
// baseline (209.418 us; speedup 1.0000x reference)
//
#include <hip/hip_runtime.h>

typedef __bf16 bf16;
typedef __bf16 bf16x8 __attribute__((ext_vector_type(8)));
typedef __bf16 bf16x4 __attribute__((ext_vector_type(4)));
typedef float  f32x4  __attribute__((ext_vector_type(4)));

#define MFMA_BF16(a, b, c) __builtin_amdgcn_mfma_f32_16x16x32_bf16((a), (b), (c), 0, 0, 0)

// Problem constants: B=2, L=2048, E=1024, H=16, D=64; M=B*L=4096, K=N=E=1024.

__device__ __forceinline__ void async_load16(const bf16* g, const bf16* l) {
    auto gp = (const __attribute__((address_space(1))) unsigned int*)(unsigned long long)(const void*)g;
    auto lp = (__attribute__((address_space(3))) unsigned int*)(unsigned int)(unsigned long long)(const void*)l;
    __builtin_amdgcn_global_load_lds(gp, lp, 16, 0, 0);
}

// ---------------------------------------------------------------------------
// fp32 -> bf16 conversion. Flat 1D grid (16384 blocks), 4 elems/thread.
// Layout: 3 activations of 2^22 elems, then 4 weights of 2^20 elems.
__global__ void cvt_bf16_kernel(
    const float* __restrict__ s0, const float* __restrict__ s1, const float* __restrict__ s2,
    const float* __restrict__ s3, const float* __restrict__ s4, const float* __restrict__ s5,
    const float* __restrict__ s6,
    bf16* __restrict__ d0, bf16* __restrict__ d1, bf16* __restrict__ d2,
    bf16* __restrict__ d3, bf16* __restrict__ d4, bf16* __restrict__ d5,
    bf16* __restrict__ d6)
{
    unsigned e = (blockIdx.x * 256 + threadIdx.x) * 4;
    const float* src; bf16* dst; unsigned off;
    if (e < 12582912u) {
        unsigned which = e >> 22;
        src = which == 0 ? s0 : (which == 1 ? s1 : s2);
        dst = which == 0 ? d0 : (which == 1 ? d1 : d2);
        off = e & 4194303u;
    } else {
        unsigned ew = e - 12582912u;
        unsigned which = ew >> 20;
        src = which == 0 ? s3 : (which == 1 ? s4 : (which == 2 ? s5 : s6));
        dst = which == 0 ? d3 : (which == 1 ? d4 : (which == 2 ? d5 : d6));
        off = ew & 1048575u;
    }
    float4 f = *(const float4*)(src + off);
    bf16x4 o;
    o.x = (bf16)f.x; o.y = (bf16)f.y; o.z = (bf16)f.z; o.w = (bf16)f.w;
    *(bf16x4*)(dst + off) = o;
}

// ---------------------------------------------------------------------------
// Tiled bf16 GEMM, BM=128 x BN (template), BK=32 x 2 stripes/barrier,
// 4 waves (2x2).
//
// XCD-aware tile remap (T1): HW assigns xcd = blockid % 8, and blockid =
// blockIdx.x + 8*blockIdx.y, so without remap each XCD got ONE feature-tile
// x ALL token-tiles -> zero B-panel reuse inside an XCD L2 (measured 101 MB
// FETCH vs ~30 MB ideal). Remap: c = flat&7 (the XCD), j = flat>>3;
// feature_tile = j&7, token_tile = c*(gy/8) + (j>>3). Per-XCD working set =
// weights 2 MB + token-panels 1 MB < 4 MB L2.  [R3: gemm4<128> left top-5]
//
// Two BK=32 stripes staged per barrier pair: halves lockstep drains (32->16).
//
// Orientation per output so the 4 r-values (C/D rows) are address-consecutive
// in the destination -> all stores bf16x4/float4:
//  z=0 (A=Wq, B=Xq): +bq, *0.125*log2e -> Qs [B,H,L,D]
//  z=1 (A=Wk, B=Xk): -> Ksw fragment-major (d lands on j)
//  z=2 (A=Xv, B=Wv): -> Vsw fragment-major (token lands on j)
//  z=3 (A=Wo, B=attn): +bo -> out fp32 (feature-contiguous float4)
template<int BN>
__global__ __launch_bounds__(256, (BN == 128) ? 2 : 4) void gemm4_kernel(
    const bf16* __restrict__ Xq, const bf16* __restrict__ Xk, const bf16* __restrict__ Xv,
    const bf16* __restrict__ Ao,
    const bf16* __restrict__ Wq, const bf16* __restrict__ Wk, const bf16* __restrict__ Wv,
    const bf16* __restrict__ Wo,
    const float* __restrict__ bq, const float* __restrict__ bo,
    bf16* __restrict__ Qs, bf16* __restrict__ Ksw, bf16* __restrict__ Vsw,
    float* __restrict__ out, int zbase)
{
    const int z = zbase + blockIdx.z;
    const bf16 *Amat, *Bmat;
    if (z == 0)      { Amat = Wq; Bmat = Xq; }
    else if (z == 1) { Amat = Wk; Bmat = Xk; }
    else if (z == 2) { Amat = Xv; Bmat = Wv; }
    else             { Amat = Wo; Bmat = Ao; }

    // XCD-aware remap (bijective: gy is a multiple of 8 for both launches)
    const int flat = blockIdx.x + 8 * blockIdx.y;
    const int c    = flat & 7;           // XCD (blockid % 8)
    const int j    = flat >> 3;          // position within this XCD's chunk
    const int ft   = j & 7;              // feature tile (8 x 128)
    const int tt   = c * (gridDim.y >> 3) + (j >> 3);  // token tile

    const int m0 = (z == 2 ? tt : ft) * 128;
    const int n0 = (z == 2 ? ft : tt) * BN;

    __shared__ __align__(16) bf16 lA[2][128 * 32];
    __shared__ __align__(16) bf16 lB[2][BN * 32];

    const int tid  = threadIdx.x;
    const int w    = tid >> 6;
    const int lane = tid & 63;
    const int lm   = lane & 15;
    const int g    = lane >> 4;
    const int wm   = (w & 1) * 64;
    const int wn   = (w >> 1) * (BN / 2);
    constexpr int NT = BN / 32;
    constexpr int T  = (128 + BN) / 64;

    f32x4 acc[4][NT] = {};

    for (int kb2 = 0; kb2 < 16; kb2++) {
        __syncthreads();
#pragma unroll
        for (int st = 0; st < 2; st++) {
            int kb = kb2 * 2 + st;
#pragma unroll
            for (int t = 0; t < T; t++) {
                int s   = (t * 4 + w) * 64 + lane;
                int row = s >> 2;
                int gs  = s & 3;
                int gg  = gs ^ ((row >> 1) & 3);
                if (row < 128)
                    async_load16(Amat + (size_t)(m0 + row) * 1024 + kb * 32 + gg * 8,
                                 lA[st] + s * 8);
                else
                    async_load16(Bmat + (size_t)(n0 + row - 128) * 1024 + kb * 32 + gg * 8,
                                 lB[st] + (s - 512) * 8);
            }
        }
        __syncthreads();

#pragma unroll
        for (int st = 0; st < 2; st++) {
            bf16x8 af[4], bfr[NT];
#pragma unroll
            for (int mt = 0; mt < 4; mt++) {
                int row = wm + mt * 16 + lm;
                af[mt] = *(const bf16x8*)(lA[st] + row * 32 + ((g ^ ((row >> 1) & 3)) << 3));
            }
#pragma unroll
            for (int nt = 0; nt < NT; nt++) {
                int row = wn + nt * 16 + lm;
                bfr[nt] = *(const bf16x8*)(lB[st] + row * 32 + ((g ^ ((row >> 1) & 3)) << 3));
            }
#pragma unroll
            for (int mt = 0; mt < 4; mt++)
#pragma unroll
                for (int nt = 0; nt < NT; nt++)
                    acc[mt][nt] = MFMA_BF16(af[mt], bfr[nt], acc[mt][nt]);
        }
    }

    if (z == 3) {
#pragma unroll
        for (int mt = 0; mt < 4; mt++) {
            int mb = m0 + wm + mt * 16 + g * 4;
            f32x4 bov = *(const f32x4*)(bo + mb);
#pragma unroll
            for (int nt = 0; nt < NT; nt++) {
                int n = n0 + wn + nt * 16 + lm;
                f32x4 val;
#pragma unroll
                for (int r = 0; r < 4; r++) val[r] = acc[mt][nt][r] + bov[r];
                *(f32x4*)(out + (size_t)n * 1024 + mb) = val;
            }
        }
    } else if (z == 2) {
#pragma unroll
        for (int mt = 0; mt < 4; mt++) {
            int mb   = m0 + wm + mt * 16 + g * 4;
            int b    = mb >> 11;
            int lpos = mb & 2047;
            int kb2  = lpos >> 6, kc = (lpos >> 5) & 1, gv = (lpos >> 3) & 3, j0 = lpos & 7;
#pragma unroll
            for (int nt = 0; nt < NT; nt++) {
                int n = n0 + wn + nt * 16 + lm;
                int h = n >> 6, mt2 = (n >> 4) & 3, lmv = n & 15;
                bf16x4 ov;
#pragma unroll
                for (int r = 0; r < 4; r++) ov[r] = (bf16)acc[mt][nt][r];
                *(bf16x4*)(Vsw + (size_t)(b * 16 + h) * 131072 +
                           (size_t)((kb2 * 8 + mt2 * 2 + kc) * 64 + gv * 16 + lmv) * 8 + j0) = ov;
            }
        }
    } else if (z == 1) {
#pragma unroll
        for (int mt = 0; mt < 4; mt++) {
            int mb = m0 + wm + mt * 16 + g * 4;
            int h  = mb >> 6;
            int f  = (mb >> 5) & 1, gk = (mb >> 3) & 3, j0 = mb & 7;
#pragma unroll
            for (int nt = 0; nt < NT; nt++) {
                int n    = n0 + wn + nt * 16 + lm;
                int b    = n >> 11;
                int lpos = n & 2047;
                int kb2  = lpos >> 6;
                int rem  = lpos & 63;
                int cc   = ((rem >> 4) & 2) | ((rem >> 2) & 1);
                int lmk  = ((rem >> 1) & 12) | (rem & 3);
                bf16x4 ov;
#pragma unroll
                for (int r = 0; r < 4; r++) ov[r] = (bf16)acc[mt][nt][r];
                *(bf16x4*)(Ksw + (size_t)(b * 16 + h) * 131072 +
                           (size_t)((kb2 * 8 + cc * 2 + f) * 64 + gk * 16 + lmk) * 8 + j0) = ov;
            }
        }
    } else {
        const float qscale = 0.18033688011112042f;  // 1/8 * log2(e)
#pragma unroll
        for (int mt = 0; mt < 4; mt++) {
            int mb  = m0 + wm + mt * 16 + g * 4;
            int h   = mb >> 6;
            int dd0 = mb & 63;
            f32x4 bqv = *(const f32x4*)(bq + mb);
#pragma unroll
            for (int nt = 0; nt < NT; nt++) {
                int n    = n0 + wn + nt * 16 + lm;
                int b    = n >> 11;
                int lpos = n & 2047;
                bf16x4 ov;
#pragma unroll
                for (int r = 0; r < 4; r++)
                    ov[r] = (bf16)((acc[mt][nt][r] + bqv[r]) * qscale);
                *(bf16x4*)(Qs + (size_t)((b * 16 + h) * 2048 + lpos) * 64 + dd0) = ov;
            }
        }
    }
}

// ---------------------------------------------------------------------------
// Flash attention v7: OCCUPANCY. R0-R4 showed three different memory
// structures (drain-0 LDS / register-direct / counted-vmcnt LDS) all land at
// 43-50 us with MfmaUtil ~27-29%: memory scheduling is NOT the limiter. The
// invariant was 2 waves/SIMD (512 blocks x 4 waves = 8 waves/CU) against a
// serial per-iter chain QK->softmax->PV of ~3255 cyc wall vs ~550 cyc pipe
// work. v7 keeps the grid (512 blocks, 1 bh x 128 q-rows each, 4 heads/XCD
// so K/V stays L2-resident) but runs 8 WAVES of 16 q-rows each: per-wave
// work halves, 4 waves/SIMD overlap the chain. K/V staged once per block
// (unchanged L2 traffic), 3-buf counted-vmcnt pipeline (never drain to 0):
//   per iter: s_waitcnt vmcnt(2) (my 2 stripe-kb loads landed; stripe-kb+1
//             stays in flight) -> s_barrier -> issue STAGE(kb+2) -> compute.
// Output staging LDS is aliased onto the K/V buffers after the loop (one
// __syncthreads separates) so total LDS = 48 KB.
__global__ __launch_bounds__(512, 4) void attn_kernel(
    const bf16* __restrict__ Qs, const bf16* __restrict__ Ksw,
    const bf16* __restrict__ Vsw, bf16* __restrict__ attn)
{
    const int tid  = threadIdx.x;
    const int w    = tid >> 6;        // 0..7
    const int lane = tid & 63;
    const int lm   = lane & 15;
    const int g    = lane >> 4;
    const int i    = blockIdx.x;
    const int bh   = ((i & 7) << 2) | ((i >> 3) & 3);  // 4 heads per XCD
    const int q0   = (i >> 5) * 128 + w * 16;

    const bf16* Qh = Qs  + (size_t)bh * 131072;
    const bf16* Kh = Ksw + (size_t)bh * 131072;
    const bf16* Vh = Vsw + (size_t)bh * 131072;

    // 48 KB: kbuf = smem[buf*4096], vbuf = smem[12288 + buf*4096], buf=0..2.
    // After the loop (separated by __syncthreads) the front 18 KB is reused
    // as the per-wave output-staging area.
    __shared__ __align__(16) bf16 smem[24576];

    // Q fragment (B operand): lane lm = q-row, k(=d) = f*32 + g*8 + j
    bf16x8 qf[2];
#pragma unroll
    for (int f = 0; f < 2; f++)
        qf[f] = *(const bf16x8*)(Qh + (size_t)(q0 + lm) * 64 + f * 32 + g * 8);

    // stage stripe `sb` into buffer `buf`: 16 x 1KB slots (8 K + 8 V),
    // wave w does slots {2w, 2w+1} -> 2 global_load_lds per wave
#define STAGE(sb, buf)                                                             \
    do {                                                                           \
        _Pragma("unroll")                                                          \
        for (int t = 0; t < 2; t++) {                                              \
            int slot = w * 2 + t;                                                  \
            if (slot < 8)                                                          \
                async_load16(Kh + ((size_t)((sb) * 8 + slot) * 64 + lane) * 8,     \
                             smem + (buf) * 4096 + (slot * 64 + lane) * 8);        \
            else                                                                   \
                async_load16(Vh + ((size_t)((sb) * 8 + slot - 8) * 64 + lane) * 8, \
                             smem + 12288 + (buf) * 4096 + ((slot - 8) * 64 + lane) * 8); \
        }                                                                          \
    } while (0)

    // prologue: stripes 0 and 1 in flight (4 loads/wave)
    STAGE(0, 0);
    STAGE(1, 1);

    const f32x4 fzero = {0.0f, 0.0f, 0.0f, 0.0f};
    f32x4 o[4] = {};
    float lsum = 0.0f;

    int cur = 0;
    for (int kb = 0; kb < 32; kb++) {
        // stripe kb's 2 loads retired; stripe kb+1's 2 remain in flight
        if (kb < 31)
            asm volatile("s_waitcnt vmcnt(2)" ::: "memory");
        else
            asm volatile("s_waitcnt vmcnt(0)" ::: "memory");
        __builtin_amdgcn_s_barrier();
        __builtin_amdgcn_sched_barrier(0);

        if (kb < 30) {
            int nb = cur + 2; if (nb >= 3) nb -= 3;
            STAGE(kb + 2, nb);
        }

        const bf16* kc_ = smem + cur * 4096;
        const bf16* vc_ = smem + 12288 + cur * 4096;

        // S^T: s[c][r] = S at k = 32*(c>>1) + 8g + 4*(c&1) + r, q = lm
        f32x4 s[4];
        __builtin_amdgcn_s_setprio(1);
#pragma unroll
        for (int c = 0; c < 4; c++) {
            bf16x8 kf0 = *(const bf16x8*)(kc_ + ((c * 2 + 0) * 64 + lane) * 8);
            bf16x8 kf1 = *(const bf16x8*)(kc_ + ((c * 2 + 1) * 64 + lane) * 8);
            s[c] = MFMA_BF16(kf0, qf[0], fzero);
            s[c] = MFMA_BF16(kf1, qf[1], s[c]);
        }
        __builtin_amdgcn_s_setprio(0);

        // p = exp2(s) -> PV B-fragments (k = 32*kc + 8g + j); VALU denominator
        bf16x8 pb[2];
        float part = 0.0f;
#pragma unroll
        for (int kc = 0; kc < 2; kc++)
#pragma unroll
            for (int r = 0; r < 4; r++) {
                float p0 = __builtin_amdgcn_exp2f(s[2 * kc][r]);
                float p1 = __builtin_amdgcn_exp2f(s[2 * kc + 1][r]);
                pb[kc][r]     = (bf16)p0;
                pb[kc][r + 4] = (bf16)p1;
                part += p0 + p1;
            }
        lsum += part;

        // O^T += V^T P
        __builtin_amdgcn_s_setprio(1);
#pragma unroll
        for (int kc = 0; kc < 2; kc++)
#pragma unroll
            for (int mt = 0; mt < 4; mt++) {
                bf16x8 vf = *(const bf16x8*)(vc_ + ((mt * 2 + kc) * 64 + lane) * 8);
                o[mt] = MFMA_BF16(vf, pb[kc], o[mt]);
            }
        __builtin_amdgcn_s_setprio(0);

        cur += 1; if (cur >= 3) cur -= 3;
    }
#undef STAGE

    // finish denominator: reduce across quads (g = lane>>4)
    lsum += __shfl_xor(lsum, 16);
    lsum += __shfl_xor(lsum, 32);

    // staging buffers dead; reuse LDS for output re-layout
    __syncthreads();
    bf16* ostw = smem + w * 1152;   // 16 rows x 72 (pad 8) per wave

    const int b = bh >> 4, h = bh & 15;
    float inv = 1.0f / lsum;
#pragma unroll
    for (int mt = 0; mt < 4; mt++) {
        bf16x4 ov;
#pragma unroll
        for (int r = 0; r < 4; r++) ov[r] = (bf16)(o[mt][r] * inv);
        *(bf16x4*)(ostw + lm * 72 + mt * 16 + g * 4) = ov;
    }
#pragma unroll
    for (int it = 0; it < 2; it++) {
        int cc = it * 64 + lane;
        int q  = cc >> 3, ch = cc & 7;
        bf16x8 t = *(const bf16x8*)(ostw + q * 72 + ch * 8);
        *(bf16x8*)(attn + (size_t)(b * 2048 + q0 + q) * 1024 + h * 64 + ch * 8) = t;
    }
}

// ---------------------------------------------------------------------------
extern "C" void kernel_launch(void* const* d_in, const int* in_sizes, int n_in,
                              void* d_out, int out_size, void* d_ws, size_t ws_size,
                              hipStream_t stream) {
    const float* query = (const float*)d_in[0];
    const float* key   = (const float*)d_in[1];
    const float* value = (const float*)d_in[2];
    const float* Wq    = (const float*)d_in[3];
    const float* bq    = (const float*)d_in[4];
    const float* Wk    = (const float*)d_in[5];
    const float* Wv    = (const float*)d_in[6];
    const float* Wo    = (const float*)d_in[7];
    const float* bo    = (const float*)d_in[8];

    char* ws = (char*)d_ws;
    bf16* Xq  = (bf16*)(ws);
    bf16* Xk  = (bf16*)(ws + ((size_t)8  << 20));
    bf16* Xv  = (bf16*)(ws + ((size_t)16 << 20));
    bf16* Wqb = (bf16*)(ws + ((size_t)24 << 20));
    bf16* Wkb = (bf16*)(ws + ((size_t)26 << 20));
    bf16* Wvb = (bf16*)(ws + ((size_t)28 << 20));
    bf16* Wob = (bf16*)(ws + ((size_t)30 << 20));
    bf16* Qs  = (bf16*)(ws + ((size_t)32 << 20));
    bf16* Ksw = (bf16*)(ws + ((size_t)40 << 20));
    bf16* Vsw = (bf16*)(ws + ((size_t)48 << 20));
    bf16* attn = Xq;  // Xq dead after projections

    cvt_bf16_kernel<<<dim3(16384, 1, 1), 256, 0, stream>>>(
        query, key, value, Wq, Wk, Wv, Wo, Xq, Xk, Xv, Wqb, Wkb, Wvb, Wob);

    gemm4_kernel<128><<<dim3(8, 32, 3), 256, 0, stream>>>(
        Xq, Xk, Xv, attn, Wqb, Wkb, Wvb, Wob, bq, bo, Qs, Ksw, Vsw, (float*)d_out, 0);

    attn_kernel<<<dim3(512, 1, 1), 512, 0, stream>>>(Qs, Ksw, Vsw, attn);

    gemm4_kernel<64><<<dim3(8, 64, 1), 256, 0, stream>>>(
        Xq, Xk, Xv, attn, Wqb, Wkb, Wvb, Wob, bq, bo, Qs, Ksw, Vsw, (float*)d_out, 3);
}

// Round 6
// 207.971 us; speedup vs baseline: 1.0070x; 1.0070x over previous
//
#include <hip/hip_runtime.h>

typedef __bf16 bf16;
typedef __bf16 bf16x8 __attribute__((ext_vector_type(8)));
typedef __bf16 bf16x4 __attribute__((ext_vector_type(4)));
typedef float  f32x4  __attribute__((ext_vector_type(4)));

#define MFMA_BF16(a, b, c) __builtin_amdgcn_mfma_f32_16x16x32_bf16((a), (b), (c), 0, 0, 0)

// Problem constants: B=2, L=2048, E=1024, H=16, D=64; M=B*L=4096, K=N=E=1024.

__device__ __forceinline__ void async_load16(const bf16* g, const bf16* l) {
    auto gp = (const __attribute__((address_space(1))) unsigned int*)(unsigned long long)(const void*)g;
    auto lp = (__attribute__((address_space(3))) unsigned int*)(unsigned int)(unsigned long long)(const void*)l;
    __builtin_amdgcn_global_load_lds(gp, lp, 16, 0, 0);
}

// ---------------------------------------------------------------------------
// fp32 -> bf16 conversion. Flat 1D grid (16384 blocks), 4 elems/thread.
// Layout: 3 activations of 2^22 elems, then 4 weights of 2^20 elems.
__global__ void cvt_bf16_kernel(
    const float* __restrict__ s0, const float* __restrict__ s1, const float* __restrict__ s2,
    const float* __restrict__ s3, const float* __restrict__ s4, const float* __restrict__ s5,
    const float* __restrict__ s6,
    bf16* __restrict__ d0, bf16* __restrict__ d1, bf16* __restrict__ d2,
    bf16* __restrict__ d3, bf16* __restrict__ d4, bf16* __restrict__ d5,
    bf16* __restrict__ d6)
{
    unsigned e = (blockIdx.x * 256 + threadIdx.x) * 4;
    const float* src; bf16* dst; unsigned off;
    if (e < 12582912u) {
        unsigned which = e >> 22;
        src = which == 0 ? s0 : (which == 1 ? s1 : s2);
        dst = which == 0 ? d0 : (which == 1 ? d1 : d2);
        off = e & 4194303u;
    } else {
        unsigned ew = e - 12582912u;
        unsigned which = ew >> 20;
        src = which == 0 ? s3 : (which == 1 ? s4 : (which == 2 ? s5 : s6));
        dst = which == 0 ? d3 : (which == 1 ? d4 : (which == 2 ? d5 : d6));
        off = ew & 1048575u;
    }
    float4 f = *(const float4*)(src + off);
    bf16x4 o;
    o.x = (bf16)f.x; o.y = (bf16)f.y; o.z = (bf16)f.z; o.w = (bf16)f.w;
    *(bf16x4*)(dst + off) = o;
}

// ---------------------------------------------------------------------------
// Tiled bf16 GEMM, BM=128 x BN (template), BK=32 x 2 stripes/barrier,
// 4 waves (2x2).
//
// XCD-aware tile remap (T1): HW assigns xcd = blockid % 8, and blockid =
// blockIdx.x + 8*blockIdx.y, so without remap each XCD got ONE feature-tile
// x ALL token-tiles -> zero B-panel reuse inside an XCD L2 (measured 101 MB
// FETCH vs ~30 MB ideal). Remap: c = flat&7 (the XCD), j = flat>>3;
// feature_tile = j&7, token_tile = c*(gy/8) + (j>>3). Per-XCD working set =
// weights 2 MB + token-panels 1 MB < 4 MB L2.  [R3: gemm4<128> left top-5]
//
// Two BK=32 stripes staged per barrier pair: halves lockstep drains (32->16).
//
// Orientation per output so the 4 r-values (C/D rows) are address-consecutive
// in the destination -> all stores bf16x4/float4:
//  z=0 (A=Wq, B=Xq): +bq, *0.125*log2e -> Qs [B,H,L,D]
//  z=1 (A=Wk, B=Xk): -> Ksw fragment-major (d lands on j)
//  z=2 (A=Xv, B=Wv): -> Vsw fragment-major (token lands on j)
//  z=3 (A=Wo, B=attn): +bo -> out fp32 (feature-contiguous float4)
template<int BN>
__global__ __launch_bounds__(256, (BN == 128) ? 2 : 4) void gemm4_kernel(
    const bf16* __restrict__ Xq, const bf16* __restrict__ Xk, const bf16* __restrict__ Xv,
    const bf16* __restrict__ Ao,
    const bf16* __restrict__ Wq, const bf16* __restrict__ Wk, const bf16* __restrict__ Wv,
    const bf16* __restrict__ Wo,
    const float* __restrict__ bq, const float* __restrict__ bo,
    bf16* __restrict__ Qs, bf16* __restrict__ Ksw, bf16* __restrict__ Vsw,
    float* __restrict__ out, int zbase)
{
    const int z = zbase + blockIdx.z;
    const bf16 *Amat, *Bmat;
    if (z == 0)      { Amat = Wq; Bmat = Xq; }
    else if (z == 1) { Amat = Wk; Bmat = Xk; }
    else if (z == 2) { Amat = Xv; Bmat = Wv; }
    else             { Amat = Wo; Bmat = Ao; }

    // XCD-aware remap (bijective: gy is a multiple of 8 for both launches)
    const int flat = blockIdx.x + 8 * blockIdx.y;
    const int c    = flat & 7;           // XCD (blockid % 8)
    const int j    = flat >> 3;          // position within this XCD's chunk
    const int ft   = j & 7;              // feature tile (8 x 128)
    const int tt   = c * (gridDim.y >> 3) + (j >> 3);  // token tile

    const int m0 = (z == 2 ? tt : ft) * 128;
    const int n0 = (z == 2 ? ft : tt) * BN;

    __shared__ __align__(16) bf16 lA[2][128 * 32];
    __shared__ __align__(16) bf16 lB[2][BN * 32];

    const int tid  = threadIdx.x;
    const int w    = tid >> 6;
    const int lane = tid & 63;
    const int lm   = lane & 15;
    const int g    = lane >> 4;
    const int wm   = (w & 1) * 64;
    const int wn   = (w >> 1) * (BN / 2);
    constexpr int NT = BN / 32;
    constexpr int T  = (128 + BN) / 64;

    f32x4 acc[4][NT] = {};

    for (int kb2 = 0; kb2 < 16; kb2++) {
        __syncthreads();
#pragma unroll
        for (int st = 0; st < 2; st++) {
            int kb = kb2 * 2 + st;
#pragma unroll
            for (int t = 0; t < T; t++) {
                int s   = (t * 4 + w) * 64 + lane;
                int row = s >> 2;
                int gs  = s & 3;
                int gg  = gs ^ ((row >> 1) & 3);
                if (row < 128)
                    async_load16(Amat + (size_t)(m0 + row) * 1024 + kb * 32 + gg * 8,
                                 lA[st] + s * 8);
                else
                    async_load16(Bmat + (size_t)(n0 + row - 128) * 1024 + kb * 32 + gg * 8,
                                 lB[st] + (s - 512) * 8);
            }
        }
        __syncthreads();

#pragma unroll
        for (int st = 0; st < 2; st++) {
            bf16x8 af[4], bfr[NT];
#pragma unroll
            for (int mt = 0; mt < 4; mt++) {
                int row = wm + mt * 16 + lm;
                af[mt] = *(const bf16x8*)(lA[st] + row * 32 + ((g ^ ((row >> 1) & 3)) << 3));
            }
#pragma unroll
            for (int nt = 0; nt < NT; nt++) {
                int row = wn + nt * 16 + lm;
                bfr[nt] = *(const bf16x8*)(lB[st] + row * 32 + ((g ^ ((row >> 1) & 3)) << 3));
            }
#pragma unroll
            for (int mt = 0; mt < 4; mt++)
#pragma unroll
                for (int nt = 0; nt < NT; nt++)
                    acc[mt][nt] = MFMA_BF16(af[mt], bfr[nt], acc[mt][nt]);
        }
    }

    if (z == 3) {
#pragma unroll
        for (int mt = 0; mt < 4; mt++) {
            int mb = m0 + wm + mt * 16 + g * 4;
            f32x4 bov = *(const f32x4*)(bo + mb);
#pragma unroll
            for (int nt = 0; nt < NT; nt++) {
                int n = n0 + wn + nt * 16 + lm;
                f32x4 val;
#pragma unroll
                for (int r = 0; r < 4; r++) val[r] = acc[mt][nt][r] + bov[r];
                *(f32x4*)(out + (size_t)n * 1024 + mb) = val;
            }
        }
    } else if (z == 2) {
#pragma unroll
        for (int mt = 0; mt < 4; mt++) {
            int mb   = m0 + wm + mt * 16 + g * 4;
            int b    = mb >> 11;
            int lpos = mb & 2047;
            int kb2  = lpos >> 6, kc = (lpos >> 5) & 1, gv = (lpos >> 3) & 3, j0 = lpos & 7;
#pragma unroll
            for (int nt = 0; nt < NT; nt++) {
                int n = n0 + wn + nt * 16 + lm;
                int h = n >> 6, mt2 = (n >> 4) & 3, lmv = n & 15;
                bf16x4 ov;
#pragma unroll
                for (int r = 0; r < 4; r++) ov[r] = (bf16)acc[mt][nt][r];
                *(bf16x4*)(Vsw + (size_t)(b * 16 + h) * 131072 +
                           (size_t)((kb2 * 8 + mt2 * 2 + kc) * 64 + gv * 16 + lmv) * 8 + j0) = ov;
            }
        }
    } else if (z == 1) {
#pragma unroll
        for (int mt = 0; mt < 4; mt++) {
            int mb = m0 + wm + mt * 16 + g * 4;
            int h  = mb >> 6;
            int f  = (mb >> 5) & 1, gk = (mb >> 3) & 3, j0 = mb & 7;
#pragma unroll
            for (int nt = 0; nt < NT; nt++) {
                int n    = n0 + wn + nt * 16 + lm;
                int b    = n >> 11;
                int lpos = n & 2047;
                int kb2  = lpos >> 6;
                int rem  = lpos & 63;
                int cc   = ((rem >> 4) & 2) | ((rem >> 2) & 1);
                int lmk  = ((rem >> 1) & 12) | (rem & 3);
                bf16x4 ov;
#pragma unroll
                for (int r = 0; r < 4; r++) ov[r] = (bf16)acc[mt][nt][r];
                *(bf16x4*)(Ksw + (size_t)(b * 16 + h) * 131072 +
                           (size_t)((kb2 * 8 + cc * 2 + f) * 64 + gk * 16 + lmk) * 8 + j0) = ov;
            }
        }
    } else {
        const float qscale = 0.18033688011112042f;  // 1/8 * log2(e)
#pragma unroll
        for (int mt = 0; mt < 4; mt++) {
            int mb  = m0 + wm + mt * 16 + g * 4;
            int h   = mb >> 6;
            int dd0 = mb & 63;
            f32x4 bqv = *(const f32x4*)(bq + mb);
#pragma unroll
            for (int nt = 0; nt < NT; nt++) {
                int n    = n0 + wn + nt * 16 + lm;
                int b    = n >> 11;
                int lpos = n & 2047;
                bf16x4 ov;
#pragma unroll
                for (int r = 0; r < 4; r++)
                    ov[r] = (bf16)((acc[mt][nt][r] + bqv[r]) * qscale);
                *(bf16x4*)(Qs + (size_t)((b * 16 + h) * 2048 + lpos) * 64 + dd0) = ov;
            }
        }
    }
}

// ---------------------------------------------------------------------------
// Flash attention v8: ARITHMETIC INTENSITY PER WAVE. Rounds 0-5 showed the
// invariant across drain-0 LDS / register-direct / counted-vmcnt / 2x-waves
// is the K/V amplification: every wave reads the WHOLE stripe while owning
// only 16-32 q-rows, so shared-operand traffic = waves x 512 KB (v5 measured:
// 1.07 GB through L1/L2 = 24.7 TB/s = 72% of the L2 ceiling -> queue-bound;
// doubling waves in v7 halved per-wave work but doubled amplification: wash).
//
// v8: register-direct (fastest structure), 64 q-rows = 4 MFMA fragments per
// wave, 4 waves/block, 256 blocks (1 block/CU, ~1 wave/SIMD):
//  - L2 demand halves (536 MB); the block's 4 waves walk the same stripe
//    sequence in phase -> followers hit L1 (stripe pair = 32 KB = L1 size).
//  - 4 INDEPENDENT fragment chains per wave: ILP replaces TLP. A single
//    wave saturates the MFMA pipe (~19 cyc/issue at the 16x16 rate) while
//    slotting softmax VALU ops between MFMA issues.
//  - Zero barriers, zero in-loop LDS, zero inter-wave coupling.
// kf reloaded (stripe kb+1) after all QK consume it -> latency hides under
// PV (~620 cyc); vf reloaded after PV -> hides under next QK+softmax.
// Occupancy will read ~6-12% -- intentional (1 wave/SIMD, ILP-fed).
__global__ __launch_bounds__(256, 1) void attn_kernel(
    const bf16* __restrict__ Qs, const bf16* __restrict__ Ksw,
    const bf16* __restrict__ Vsw, bf16* __restrict__ attn)
{
    const int tid  = threadIdx.x;
    const int w    = tid >> 6;        // 0..3
    const int lane = tid & 63;
    const int lm   = lane & 15;
    const int g    = lane >> 4;
    const int i    = blockIdx.x;      // 256 blocks
    const int bh   = ((i & 7) << 2) | ((i >> 3) & 3);  // 4 heads per XCD
    const int q0   = (i >> 5) * 256 + w * 64;          // 64 q-rows per wave

    const bf16* Qh = Qs  + (size_t)bh * 131072;
    const bf16* Kh = Ksw + (size_t)bh * 131072;
    const bf16* Vh = Vsw + (size_t)bh * 131072;

    // epilogue-only LDS: 4 waves x 64 rows x 72 (pad 8) bf16 = 36 KB
    __shared__ __align__(16) bf16 smem[4 * 64 * 72];

    // Q fragments (B operand): lane lm = q-row, k(=d) = f*32 + g*8 + j
    bf16x8 qf[4][2];
#pragma unroll
    for (int qi = 0; qi < 4; qi++)
#pragma unroll
        for (int f = 0; f < 2; f++)
            qf[qi][f] = *(const bf16x8*)(Qh + (size_t)(q0 + qi * 16 + lm) * 64 + f * 32 + g * 8);

    const f32x4 fzero = {0.0f, 0.0f, 0.0f, 0.0f};
    f32x4 o[4][4] = {};
    float lsum[4] = {0.0f, 0.0f, 0.0f, 0.0f};

    // prologue: stripe-0 fragments into registers (K: 8x1KB, V: 8x1KB)
    bf16x8 kf[8], vf[8];
#pragma unroll
    for (int t = 0; t < 8; t++)
        kf[t] = *(const bf16x8*)(Kh + ((size_t)t * 64 + lane) * 8);
#pragma unroll
    for (int t = 0; t < 8; t++)
        vf[t] = *(const bf16x8*)(Vh + ((size_t)t * 64 + lane) * 8);

    for (int kb = 0; kb < 32; kb++) {
        // next-stripe base (clamped: last iteration re-reads stripe 31, unused)
        const int kn = (kb < 31) ? kb + 1 : 31;
        const bf16* Kn = Kh + (size_t)kn * 4096;
        const bf16* Vn = Vh + (size_t)kn * 4096;

        // QK^T + softmax per fragment (4 independent chains -> ILP):
        // s[c][r] = S at k = 32*(c>>1) + 8g + 4*(c&1) + r, q = lm
        bf16x8 pb[4][2];
#pragma unroll
        for (int qi = 0; qi < 4; qi++) {
            f32x4 s[4];
#pragma unroll
            for (int c = 0; c < 4; c++) {
                s[c] = MFMA_BF16(kf[2 * c],     qf[qi][0], fzero);
                s[c] = MFMA_BF16(kf[2 * c + 1], qf[qi][1], s[c]);
            }
            float part = 0.0f;
#pragma unroll
            for (int kc = 0; kc < 2; kc++)
#pragma unroll
                for (int r = 0; r < 4; r++) {
                    float p0 = __builtin_amdgcn_exp2f(s[2 * kc][r]);
                    float p1 = __builtin_amdgcn_exp2f(s[2 * kc + 1][r]);
                    pb[qi][kc][r]     = (bf16)p0;
                    pb[qi][kc][r + 4] = (bf16)p1;
                    part += p0 + p1;
                }
            lsum[qi] += part;
        }

        // reload kf with stripe kb+1 -- latency hides under PV (32 MFMAs)
#pragma unroll
        for (int t = 0; t < 8; t++)
            kf[t] = *(const bf16x8*)(Kn + ((size_t)t * 64 + lane) * 8);

        // O^T += V^T P (shared vf fragment feeds all 4 q-fragments)
#pragma unroll
        for (int kc = 0; kc < 2; kc++)
#pragma unroll
            for (int mt = 0; mt < 4; mt++) {
                bf16x8 vfv = vf[mt * 2 + kc];
#pragma unroll
                for (int qi = 0; qi < 4; qi++)
                    o[qi][mt] = MFMA_BF16(vfv, pb[qi][kc], o[qi][mt]);
            }

        // reload vf with stripe kb+1 -- hides under next QK^T + softmax
#pragma unroll
        for (int t = 0; t < 8; t++)
            vf[t] = *(const bf16x8*)(Vn + ((size_t)t * 64 + lane) * 8);
    }

    // finish denominators: k lives on (in-lane, quad); reduce across quads
#pragma unroll
    for (int qi = 0; qi < 4; qi++) {
        lsum[qi] += __shfl_xor(lsum[qi], 16);
        lsum[qi] += __shfl_xor(lsum[qi], 32);
    }

    // normalized O -> per-wave LDS region (stride 72), then 16B/lane stores
    const int b = bh >> 4, h = bh & 15;
    bf16* ostw = smem + w * 4608;
#pragma unroll
    for (int qi = 0; qi < 4; qi++) {
        float inv = 1.0f / lsum[qi];
#pragma unroll
        for (int mt = 0; mt < 4; mt++) {
            bf16x4 ov;
#pragma unroll
            for (int r = 0; r < 4; r++) ov[r] = (bf16)(o[qi][mt][r] * inv);
            *(bf16x4*)(ostw + (qi * 16 + lm) * 72 + mt * 16 + g * 4) = ov;
        }
    }
#pragma unroll
    for (int it = 0; it < 8; it++) {
        int cc = it * 64 + lane;
        int q  = cc >> 3, ch = cc & 7;
        bf16x8 t = *(const bf16x8*)(ostw + q * 72 + ch * 8);
        *(bf16x8*)(attn + (size_t)(b * 2048 + q0 + q) * 1024 + h * 64 + ch * 8) = t;
    }
}

// ---------------------------------------------------------------------------
extern "C" void kernel_launch(void* const* d_in, const int* in_sizes, int n_in,
                              void* d_out, int out_size, void* d_ws, size_t ws_size,
                              hipStream_t stream) {
    const float* query = (const float*)d_in[0];
    const float* key   = (const float*)d_in[1];
    const float* value = (const float*)d_in[2];
    const float* Wq    = (const float*)d_in[3];
    const float* bq    = (const float*)d_in[4];
    const float* Wk    = (const float*)d_in[5];
    const float* Wv    = (const float*)d_in[6];
    const float* Wo    = (const float*)d_in[7];
    const float* bo    = (const float*)d_in[8];

    char* ws = (char*)d_ws;
    bf16* Xq  = (bf16*)(ws);
    bf16* Xk  = (bf16*)(ws + ((size_t)8  << 20));
    bf16* Xv  = (bf16*)(ws + ((size_t)16 << 20));
    bf16* Wqb = (bf16*)(ws + ((size_t)24 << 20));
    bf16* Wkb = (bf16*)(ws + ((size_t)26 << 20));
    bf16* Wvb = (bf16*)(ws + ((size_t)28 << 20));
    bf16* Wob = (bf16*)(ws + ((size_t)30 << 20));
    bf16* Qs  = (bf16*)(ws + ((size_t)32 << 20));
    bf16* Ksw = (bf16*)(ws + ((size_t)40 << 20));
    bf16* Vsw = (bf16*)(ws + ((size_t)48 << 20));
    bf16* attn = Xq;  // Xq dead after projections

    cvt_bf16_kernel<<<dim3(16384, 1, 1), 256, 0, stream>>>(
        query, key, value, Wq, Wk, Wv, Wo, Xq, Xk, Xv, Wqb, Wkb, Wvb, Wob);

    gemm4_kernel<128><<<dim3(8, 32, 3), 256, 0, stream>>>(
        Xq, Xk, Xv, attn, Wqb, Wkb, Wvb, Wob, bq, bo, Qs, Ksw, Vsw, (float*)d_out, 0);

    attn_kernel<<<dim3(256, 1, 1), 256, 0, stream>>>(Qs, Ksw, Vsw, attn);

    gemm4_kernel<64><<<dim3(8, 64, 1), 256, 0, stream>>>(
        Xq, Xk, Xv, attn, Wqb, Wkb, Wvb, Wob, bq, bo, Qs, Ksw, Vsw, (float*)d_out, 3);
}

// Round 7
// 201.547 us; speedup vs baseline: 1.0391x; 1.0319x over previous
//
#include <hip/hip_runtime.h>

typedef __bf16 bf16;
typedef __bf16 bf16x8 __attribute__((ext_vector_type(8)));
typedef __bf16 bf16x4 __attribute__((ext_vector_type(4)));
typedef float  f32x4  __attribute__((ext_vector_type(4)));

#define MFMA_BF16(a, b, c) __builtin_amdgcn_mfma_f32_16x16x32_bf16((a), (b), (c), 0, 0, 0)

// Problem constants: B=2, L=2048, E=1024, H=16, D=64; M=B*L=4096, K=N=E=1024.

__device__ __forceinline__ void async_load16(const bf16* g, const bf16* l) {
    auto gp = (const __attribute__((address_space(1))) unsigned int*)(unsigned long long)(const void*)g;
    auto lp = (__attribute__((address_space(3))) unsigned int*)(unsigned int)(unsigned long long)(const void*)l;
    __builtin_amdgcn_global_load_lds(gp, lp, 16, 0, 0);
}

// ---------------------------------------------------------------------------
// fp32 -> bf16 conversion. Flat 1D grid (16384 blocks), 4 elems/thread.
// Layout: 3 activations of 2^22 elems, then 4 weights of 2^20 elems.
__global__ void cvt_bf16_kernel(
    const float* __restrict__ s0, const float* __restrict__ s1, const float* __restrict__ s2,
    const float* __restrict__ s3, const float* __restrict__ s4, const float* __restrict__ s5,
    const float* __restrict__ s6,
    bf16* __restrict__ d0, bf16* __restrict__ d1, bf16* __restrict__ d2,
    bf16* __restrict__ d3, bf16* __restrict__ d4, bf16* __restrict__ d5,
    bf16* __restrict__ d6)
{
    unsigned e = (blockIdx.x * 256 + threadIdx.x) * 4;
    const float* src; bf16* dst; unsigned off;
    if (e < 12582912u) {
        unsigned which = e >> 22;
        src = which == 0 ? s0 : (which == 1 ? s1 : s2);
        dst = which == 0 ? d0 : (which == 1 ? d1 : d2);
        off = e & 4194303u;
    } else {
        unsigned ew = e - 12582912u;
        unsigned which = ew >> 20;
        src = which == 0 ? s3 : (which == 1 ? s4 : (which == 2 ? s5 : s6));
        dst = which == 0 ? d3 : (which == 1 ? d4 : (which == 2 ? d5 : d6));
        off = ew & 1048575u;
    }
    float4 f = *(const float4*)(src + off);
    bf16x4 o;
    o.x = (bf16)f.x; o.y = (bf16)f.y; o.z = (bf16)f.z; o.w = (bf16)f.w;
    *(bf16x4*)(dst + off) = o;
}

// ---------------------------------------------------------------------------
// Tiled bf16 GEMM, BM=128 x BN (template), BK=32 x 2 stripes/barrier,
// 4 waves (2x2).
//
// XCD-aware tile remap (T1): HW assigns xcd = blockid % 8, and blockid =
// blockIdx.x + 8*blockIdx.y, so without remap each XCD got ONE feature-tile
// x ALL token-tiles -> zero B-panel reuse inside an XCD L2 (measured 101 MB
// FETCH vs ~30 MB ideal). Remap: c = flat&7 (the XCD), j = flat>>3;
// feature_tile = j&7, token_tile = c*(gy/8) + (j>>3). Per-XCD working set =
// weights 2 MB + token-panels 1 MB < 4 MB L2.  [R3: gemm4<128> left top-5]
//
// Two BK=32 stripes staged per barrier pair: halves lockstep drains (32->16).
//
// Orientation per output so the 4 r-values (C/D rows) are address-consecutive
// in the destination -> all stores bf16x4/float4:
//  z=0 (A=Wq, B=Xq): +bq, *0.125*log2e -> Qs [B,H,L,D]
//  z=1 (A=Wk, B=Xk): -> Ksw fragment-major (d lands on j)
//  z=2 (A=Xv, B=Wv): -> Vsw fragment-major (token lands on j)
//  z=3 (A=Wo, B=attn): +bo -> out fp32 (feature-contiguous float4)
template<int BN>
__global__ __launch_bounds__(256, (BN == 128) ? 2 : 4) void gemm4_kernel(
    const bf16* __restrict__ Xq, const bf16* __restrict__ Xk, const bf16* __restrict__ Xv,
    const bf16* __restrict__ Ao,
    const bf16* __restrict__ Wq, const bf16* __restrict__ Wk, const bf16* __restrict__ Wv,
    const bf16* __restrict__ Wo,
    const float* __restrict__ bq, const float* __restrict__ bo,
    bf16* __restrict__ Qs, bf16* __restrict__ Ksw, bf16* __restrict__ Vsw,
    float* __restrict__ out, int zbase)
{
    const int z = zbase + blockIdx.z;
    const bf16 *Amat, *Bmat;
    if (z == 0)      { Amat = Wq; Bmat = Xq; }
    else if (z == 1) { Amat = Wk; Bmat = Xk; }
    else if (z == 2) { Amat = Xv; Bmat = Wv; }
    else             { Amat = Wo; Bmat = Ao; }

    // XCD-aware remap (bijective: gy is a multiple of 8 for both launches)
    const int flat = blockIdx.x + 8 * blockIdx.y;
    const int c    = flat & 7;           // XCD (blockid % 8)
    const int j    = flat >> 3;          // position within this XCD's chunk
    const int ft   = j & 7;              // feature tile (8 x 128)
    const int tt   = c * (gridDim.y >> 3) + (j >> 3);  // token tile

    const int m0 = (z == 2 ? tt : ft) * 128;
    const int n0 = (z == 2 ? ft : tt) * BN;

    __shared__ __align__(16) bf16 lA[2][128 * 32];
    __shared__ __align__(16) bf16 lB[2][BN * 32];

    const int tid  = threadIdx.x;
    const int w    = tid >> 6;
    const int lane = tid & 63;
    const int lm   = lane & 15;
    const int g    = lane >> 4;
    const int wm   = (w & 1) * 64;
    const int wn   = (w >> 1) * (BN / 2);
    constexpr int NT = BN / 32;
    constexpr int T  = (128 + BN) / 64;

    f32x4 acc[4][NT] = {};

    for (int kb2 = 0; kb2 < 16; kb2++) {
        __syncthreads();
#pragma unroll
        for (int st = 0; st < 2; st++) {
            int kb = kb2 * 2 + st;
#pragma unroll
            for (int t = 0; t < T; t++) {
                int s   = (t * 4 + w) * 64 + lane;
                int row = s >> 2;
                int gs  = s & 3;
                int gg  = gs ^ ((row >> 1) & 3);
                if (row < 128)
                    async_load16(Amat + (size_t)(m0 + row) * 1024 + kb * 32 + gg * 8,
                                 lA[st] + s * 8);
                else
                    async_load16(Bmat + (size_t)(n0 + row - 128) * 1024 + kb * 32 + gg * 8,
                                 lB[st] + (s - 512) * 8);
            }
        }
        __syncthreads();

#pragma unroll
        for (int st = 0; st < 2; st++) {
            bf16x8 af[4], bfr[NT];
#pragma unroll
            for (int mt = 0; mt < 4; mt++) {
                int row = wm + mt * 16 + lm;
                af[mt] = *(const bf16x8*)(lA[st] + row * 32 + ((g ^ ((row >> 1) & 3)) << 3));
            }
#pragma unroll
            for (int nt = 0; nt < NT; nt++) {
                int row = wn + nt * 16 + lm;
                bfr[nt] = *(const bf16x8*)(lB[st] + row * 32 + ((g ^ ((row >> 1) & 3)) << 3));
            }
#pragma unroll
            for (int mt = 0; mt < 4; mt++)
#pragma unroll
                for (int nt = 0; nt < NT; nt++)
                    acc[mt][nt] = MFMA_BF16(af[mt], bfr[nt], acc[mt][nt]);
        }
    }

    if (z == 3) {
#pragma unroll
        for (int mt = 0; mt < 4; mt++) {
            int mb = m0 + wm + mt * 16 + g * 4;
            f32x4 bov = *(const f32x4*)(bo + mb);
#pragma unroll
            for (int nt = 0; nt < NT; nt++) {
                int n = n0 + wn + nt * 16 + lm;
                f32x4 val;
#pragma unroll
                for (int r = 0; r < 4; r++) val[r] = acc[mt][nt][r] + bov[r];
                *(f32x4*)(out + (size_t)n * 1024 + mb) = val;
            }
        }
    } else if (z == 2) {
#pragma unroll
        for (int mt = 0; mt < 4; mt++) {
            int mb   = m0 + wm + mt * 16 + g * 4;
            int b    = mb >> 11;
            int lpos = mb & 2047;
            int kb2  = lpos >> 6, kc = (lpos >> 5) & 1, gv = (lpos >> 3) & 3, j0 = lpos & 7;
#pragma unroll
            for (int nt = 0; nt < NT; nt++) {
                int n = n0 + wn + nt * 16 + lm;
                int h = n >> 6, mt2 = (n >> 4) & 3, lmv = n & 15;
                bf16x4 ov;
#pragma unroll
                for (int r = 0; r < 4; r++) ov[r] = (bf16)acc[mt][nt][r];
                *(bf16x4*)(Vsw + (size_t)(b * 16 + h) * 131072 +
                           (size_t)((kb2 * 8 + mt2 * 2 + kc) * 64 + gv * 16 + lmv) * 8 + j0) = ov;
            }
        }
    } else if (z == 1) {
#pragma unroll
        for (int mt = 0; mt < 4; mt++) {
            int mb = m0 + wm + mt * 16 + g * 4;
            int h  = mb >> 6;
            int f  = (mb >> 5) & 1, gk = (mb >> 3) & 3, j0 = mb & 7;
#pragma unroll
            for (int nt = 0; nt < NT; nt++) {
                int n    = n0 + wn + nt * 16 + lm;
                int b    = n >> 11;
                int lpos = n & 2047;
                int kb2  = lpos >> 6;
                int rem  = lpos & 63;
                int cc   = ((rem >> 4) & 2) | ((rem >> 2) & 1);
                int lmk  = ((rem >> 1) & 12) | (rem & 3);
                bf16x4 ov;
#pragma unroll
                for (int r = 0; r < 4; r++) ov[r] = (bf16)acc[mt][nt][r];
                *(bf16x4*)(Ksw + (size_t)(b * 16 + h) * 131072 +
                           (size_t)((kb2 * 8 + cc * 2 + f) * 64 + gk * 16 + lmk) * 8 + j0) = ov;
            }
        }
    } else {
        const float qscale = 0.18033688011112042f;  // 1/8 * log2(e)
#pragma unroll
        for (int mt = 0; mt < 4; mt++) {
            int mb  = m0 + wm + mt * 16 + g * 4;
            int h   = mb >> 6;
            int dd0 = mb & 63;
            f32x4 bqv = *(const f32x4*)(bq + mb);
#pragma unroll
            for (int nt = 0; nt < NT; nt++) {
                int n    = n0 + wn + nt * 16 + lm;
                int b    = n >> 11;
                int lpos = n & 2047;
                bf16x4 ov;
#pragma unroll
                for (int r = 0; r < 4; r++)
                    ov[r] = (bf16)((acc[mt][nt][r] + bqv[r]) * qscale);
                *(bf16x4*)(Qs + (size_t)((b * 16 + h) * 2048 + lpos) * 64 + dd0) = ov;
            }
        }
    }
}

// ---------------------------------------------------------------------------
// Flash attention v9: K-SPLIT for VALU/MFMA overlap at full intensity.
// Calibrated model from v8 (1 wave/SIMD): per-SIMD per 64-token stripe the
// pipes demand VALU ~1717 cyc (exp2 @1/4 rate + bf16 cvt/pack + adds) and
// MFMA ~1240 cyc (64 x 16x16x32 @ ~19.4 cyc/SIMD); VALU > MFMA, and with 1
// wave/SIMD they serialize (m114: overlap requires separate waves). Fixed
// total q-rows means more waves at 64 q-rows/wave requires splitting K:
// the no-max softmax (p = exp2(s), no running max) makes disjoint-k partial
// (O, lsum) EXACTLY additive -- no rescale, so the combine is one LDS pass.
//
// 256 blocks x 8 waves (2 waves/SIMD, VGPR capped 256): wave w: q-chunk
// (w&3)*64 within the block's 256 rows; k-half (w>>2)*1024 tokens = 16
// stripes. Register-direct K/V fragment loads (fragment-major layout; the
// 4 in-phase waves per half share stripes via L1), software-pipelined
// reloads (kf after QK, vf after PV). Softmax writes pb elements in
// ADJACENT order from a flat unrolled p[16] so the compiler can fuse
// v_cvt_pk_bf16_f32 (removes ~60% of the cvt/insert VALU ops).
// Epilogue: waves 4-7 park partial O (f32, stride-68 pad -> conflict-free)
// + lsum in LDS; barrier; waves 0-3 add, normalize, store.
__global__ __launch_bounds__(512, 2) void attn_kernel(
    const bf16* __restrict__ Qs, const bf16* __restrict__ Ksw,
    const bf16* __restrict__ Vsw, bf16* __restrict__ attn)
{
    const int tid  = threadIdx.x;
    const int w    = tid >> 6;        // 0..7
    const int wq   = w & 3;           // q sub-chunk
    const int wk   = w >> 2;          // k half
    const int lane = tid & 63;
    const int lm   = lane & 15;
    const int g    = lane >> 4;
    const int i    = blockIdx.x;      // 256 blocks
    const int bh   = ((i & 7) << 2) | ((i >> 3) & 3);  // 4 heads per XCD
    const int q0   = (i >> 5) * 256 + wq * 64;         // 64 q-rows per wave

    const bf16* Qh = Qs  + (size_t)bh * 131072;
    const bf16* Kh = Ksw + (size_t)bh * 131072 + (size_t)wk * 65536;  // k-half base
    const bf16* Vh = Vsw + (size_t)bh * 131072 + (size_t)wk * 65536;

    // psum: 4 x 64 x 68 f32 (69.6 KB) + plsum 4 x 64 f32 (1 KB) +
    // ost: 4 waves x 64 x 72 bf16 (36 KB). Total ~107 KB -> 1 block/CU.
    __shared__ __align__(16) float psum[4][64][68];
    __shared__ float plsum[4][64];
    __shared__ __align__(16) bf16 ost[4][64 * 72];

    // Q fragments (B operand): lane lm = q-row, k(=d) = f*32 + g*8 + j
    bf16x8 qf[4][2];
#pragma unroll
    for (int qi = 0; qi < 4; qi++)
#pragma unroll
        for (int f = 0; f < 2; f++)
            qf[qi][f] = *(const bf16x8*)(Qh + (size_t)(q0 + qi * 16 + lm) * 64 + f * 32 + g * 8);

    const f32x4 fzero = {0.0f, 0.0f, 0.0f, 0.0f};
    f32x4 o[4][4] = {};
    float lsum[4] = {0.0f, 0.0f, 0.0f, 0.0f};

    // prologue: stripe-0 (of this k-half) fragments into registers
    bf16x8 kf[8], vf[8];
#pragma unroll
    for (int t = 0; t < 8; t++)
        kf[t] = *(const bf16x8*)(Kh + ((size_t)t * 64 + lane) * 8);
#pragma unroll
    for (int t = 0; t < 8; t++)
        vf[t] = *(const bf16x8*)(Vh + ((size_t)t * 64 + lane) * 8);

    for (int kb = 0; kb < 16; kb++) {
        // next-stripe base (clamped: last iteration re-reads stripe 15, unused)
        const int kn = (kb < 15) ? kb + 1 : 15;
        const bf16* Kn = Kh + (size_t)kn * 4096;
        const bf16* Vn = Vh + (size_t)kn * 4096;

        // QK^T + softmax per fragment (4 independent chains -> ILP):
        // s[c][r] = S at k = 32*(c>>1) + 8g + 4*(c&1) + r, q = lm
        bf16x8 pb[4][2];
        __builtin_amdgcn_s_setprio(1);
#pragma unroll
        for (int qi = 0; qi < 4; qi++) {
            f32x4 s[4];
#pragma unroll
            for (int c = 0; c < 4; c++) {
                s[c] = MFMA_BF16(kf[2 * c],     qf[qi][0], fzero);
                s[c] = MFMA_BF16(kf[2 * c + 1], qf[qi][1], s[c]);
            }
            // flat p[]: index kc*8 + j, j 0..3 <- s[2kc][j], j 4..7 <- s[2kc+1][j-4]
            float p[16];
#pragma unroll
            for (int c = 0; c < 4; c++)
#pragma unroll
                for (int r = 0; r < 4; r++)
                    p[(c >> 1) * 8 + (c & 1) * 4 + r] = __builtin_amdgcn_exp2f(s[c][r]);
            float part = 0.0f;
#pragma unroll
            for (int kc = 0; kc < 2; kc++)
#pragma unroll
                for (int jj = 0; jj < 8; jj++) {   // adjacent writes -> cvt_pk
                    pb[qi][kc][jj] = (bf16)p[kc * 8 + jj];
                    part += p[kc * 8 + jj];
                }
            lsum[qi] += part;
        }
        __builtin_amdgcn_s_setprio(0);

        // reload kf with next stripe -- latency hides under PV (32 MFMAs)
#pragma unroll
        for (int t = 0; t < 8; t++)
            kf[t] = *(const bf16x8*)(Kn + ((size_t)t * 64 + lane) * 8);

        // O^T += V^T P (shared vf fragment feeds all 4 q-fragments)
        __builtin_amdgcn_s_setprio(1);
#pragma unroll
        for (int kc = 0; kc < 2; kc++)
#pragma unroll
            for (int mt = 0; mt < 4; mt++) {
                bf16x8 vfv = vf[mt * 2 + kc];
#pragma unroll
                for (int qi = 0; qi < 4; qi++)
                    o[qi][mt] = MFMA_BF16(vfv, pb[qi][kc], o[qi][mt]);
            }
        __builtin_amdgcn_s_setprio(0);

        // reload vf with next stripe -- hides under next QK^T + softmax
#pragma unroll
        for (int t = 0; t < 8; t++)
            vf[t] = *(const bf16x8*)(Vn + ((size_t)t * 64 + lane) * 8);
    }

    // finish denominators: reduce across quads (full k-half per lane after)
#pragma unroll
    for (int qi = 0; qi < 4; qi++) {
        lsum[qi] += __shfl_xor(lsum[qi], 16);
        lsum[qi] += __shfl_xor(lsum[qi], 32);
    }

    // k-split combine: waves 4-7 park partials, waves 0-3 add + finish
    if (w >= 4) {
#pragma unroll
        for (int qi = 0; qi < 4; qi++)
#pragma unroll
            for (int mt = 0; mt < 4; mt++)
                *(f32x4*)(&psum[wq][qi * 16 + lm][mt * 16 + g * 4]) = o[qi][mt];
        if (g == 0)
#pragma unroll
            for (int qi = 0; qi < 4; qi++)
                plsum[wq][qi * 16 + lm] = lsum[qi];
    }
    __syncthreads();
    if (w < 4) {
        const int b = bh >> 4, h = bh & 15;
        bf16* ostw = ost[wq];
#pragma unroll
        for (int qi = 0; qi < 4; qi++) {
            float tot = lsum[qi] + plsum[wq][qi * 16 + lm];
            float inv = 1.0f / tot;
#pragma unroll
            for (int mt = 0; mt < 4; mt++) {
                f32x4 ps = *(const f32x4*)(&psum[wq][qi * 16 + lm][mt * 16 + g * 4]);
                bf16x4 ov;
#pragma unroll
                for (int r = 0; r < 4; r++)
                    ov[r] = (bf16)((o[qi][mt][r] + ps[r]) * inv);
                *(bf16x4*)(ostw + (qi * 16 + lm) * 72 + mt * 16 + g * 4) = ov;
            }
        }
        __builtin_amdgcn_s_waitcnt(0);  // lgkmcnt(0) before re-reading own region
#pragma unroll
        for (int it = 0; it < 8; it++) {
            int cc = it * 64 + lane;
            int q  = cc >> 3, ch = cc & 7;
            bf16x8 t = *(const bf16x8*)(ostw + q * 72 + ch * 8);
            *(bf16x8*)(attn + (size_t)(b * 2048 + q0 + q) * 1024 + h * 64 + ch * 8) = t;
        }
    }
}

// ---------------------------------------------------------------------------
extern "C" void kernel_launch(void* const* d_in, const int* in_sizes, int n_in,
                              void* d_out, int out_size, void* d_ws, size_t ws_size,
                              hipStream_t stream) {
    const float* query = (const float*)d_in[0];
    const float* key   = (const float*)d_in[1];
    const float* value = (const float*)d_in[2];
    const float* Wq    = (const float*)d_in[3];
    const float* bq    = (const float*)d_in[4];
    const float* Wk    = (const float*)d_in[5];
    const float* Wv    = (const float*)d_in[6];
    const float* Wo    = (const float*)d_in[7];
    const float* bo    = (const float*)d_in[8];

    char* ws = (char*)d_ws;
    bf16* Xq  = (bf16*)(ws);
    bf16* Xk  = (bf16*)(ws + ((size_t)8  << 20));
    bf16* Xv  = (bf16*)(ws + ((size_t)16 << 20));
    bf16* Wqb = (bf16*)(ws + ((size_t)24 << 20));
    bf16* Wkb = (bf16*)(ws + ((size_t)26 << 20));
    bf16* Wvb = (bf16*)(ws + ((size_t)28 << 20));
    bf16* Wob = (bf16*)(ws + ((size_t)30 << 20));
    bf16* Qs  = (bf16*)(ws + ((size_t)32 << 20));
    bf16* Ksw = (bf16*)(ws + ((size_t)40 << 20));
    bf16* Vsw = (bf16*)(ws + ((size_t)48 << 20));
    bf16* attn = Xq;  // Xq dead after projections

    cvt_bf16_kernel<<<dim3(16384, 1, 1), 256, 0, stream>>>(
        query, key, value, Wq, Wk, Wv, Wo, Xq, Xk, Xv, Wqb, Wkb, Wvb, Wob);

    gemm4_kernel<128><<<dim3(8, 32, 3), 256, 0, stream>>>(
        Xq, Xk, Xv, attn, Wqb, Wkb, Wvb, Wob, bq, bo, Qs, Ksw, Vsw, (float*)d_out, 0);

    attn_kernel<<<dim3(256, 1, 1), 512, 0, stream>>>(Qs, Ksw, Vsw, attn);

    gemm4_kernel<64><<<dim3(8, 64, 1), 256, 0, stream>>>(
        Xq, Xk, Xv, attn, Wqb, Wkb, Wvb, Wob, bq, bo, Qs, Ksw, Vsw, (float*)d_out, 3);
}

// Round 8
// 196.570 us; speedup vs baseline: 1.0654x; 1.0253x over previous
//
#include <hip/hip_runtime.h>

typedef __bf16 bf16;
typedef __bf16 bf16x8 __attribute__((ext_vector_type(8)));
typedef __bf16 bf16x4 __attribute__((ext_vector_type(4)));
typedef float  f32x4  __attribute__((ext_vector_type(4)));

#define MFMA_BF16(a, b, c) __builtin_amdgcn_mfma_f32_16x16x32_bf16((a), (b), (c), 0, 0, 0)

// Problem constants: B=2, L=2048, E=1024, H=16, D=64; M=B*L=4096, K=N=E=1024.

__device__ __forceinline__ void async_load16(const bf16* g, const bf16* l) {
    auto gp = (const __attribute__((address_space(1))) unsigned int*)(unsigned long long)(const void*)g;
    auto lp = (__attribute__((address_space(3))) unsigned int*)(unsigned int)(unsigned long long)(const void*)l;
    __builtin_amdgcn_global_load_lds(gp, lp, 16, 0, 0);
}

// ---------------------------------------------------------------------------
// fp32 -> bf16 conversion. Flat 1D grid (16384 blocks), 4 elems/thread.
// Layout: 3 activations of 2^22 elems, then 4 weights of 2^20 elems.
__global__ void cvt_bf16_kernel(
    const float* __restrict__ s0, const float* __restrict__ s1, const float* __restrict__ s2,
    const float* __restrict__ s3, const float* __restrict__ s4, const float* __restrict__ s5,
    const float* __restrict__ s6,
    bf16* __restrict__ d0, bf16* __restrict__ d1, bf16* __restrict__ d2,
    bf16* __restrict__ d3, bf16* __restrict__ d4, bf16* __restrict__ d5,
    bf16* __restrict__ d6)
{
    unsigned e = (blockIdx.x * 256 + threadIdx.x) * 4;
    const float* src; bf16* dst; unsigned off;
    if (e < 12582912u) {
        unsigned which = e >> 22;
        src = which == 0 ? s0 : (which == 1 ? s1 : s2);
        dst = which == 0 ? d0 : (which == 1 ? d1 : d2);
        off = e & 4194303u;
    } else {
        unsigned ew = e - 12582912u;
        unsigned which = ew >> 20;
        src = which == 0 ? s3 : (which == 1 ? s4 : (which == 2 ? s5 : s6));
        dst = which == 0 ? d3 : (which == 1 ? d4 : (which == 2 ? d5 : d6));
        off = ew & 1048575u;
    }
    float4 f = *(const float4*)(src + off);
    bf16x4 o;
    o.x = (bf16)f.x; o.y = (bf16)f.y; o.z = (bf16)f.z; o.w = (bf16)f.w;
    *(bf16x4*)(dst + off) = o;
}

// ---------------------------------------------------------------------------
// Tiled bf16 GEMM, BM=128 x BN (template), BK=32 x 2 stripes/barrier,
// 4 waves (2x2).
//
// XCD-aware tile remap (T1): HW assigns xcd = blockid % 8, and blockid =
// blockIdx.x + 8*blockIdx.y, so without remap each XCD got ONE feature-tile
// x ALL token-tiles -> zero B-panel reuse inside an XCD L2 (measured 101 MB
// FETCH vs ~30 MB ideal). Remap: c = flat&7 (the XCD), j = flat>>3;
// feature_tile = j&7, token_tile = c*(gy/8) + (j>>3). Per-XCD working set =
// weights 2 MB + token-panels 1 MB < 4 MB L2.  [R3: gemm4<128> left top-5]
//
// Two BK=32 stripes staged per barrier pair: halves lockstep drains (32->16).
//
// Orientation per output so the 4 r-values (C/D rows) are address-consecutive
// in the destination -> all stores bf16x4/float4:
//  z=0 (A=Wq, B=Xq): +bq, *0.125*log2e -> Qs [B,H,L,D]
//  z=1 (A=Wk, B=Xk): -> Ksw fragment-major (d lands on j)
//  z=2 (A=Xv, B=Wv): -> Vsw fragment-major (token lands on j)
//  z=3 (A=Wo, B=attn): +bo -> out fp32 (feature-contiguous float4)
template<int BN>
__global__ __launch_bounds__(256, (BN == 128) ? 2 : 4) void gemm4_kernel(
    const bf16* __restrict__ Xq, const bf16* __restrict__ Xk, const bf16* __restrict__ Xv,
    const bf16* __restrict__ Ao,
    const bf16* __restrict__ Wq, const bf16* __restrict__ Wk, const bf16* __restrict__ Wv,
    const bf16* __restrict__ Wo,
    const float* __restrict__ bq, const float* __restrict__ bo,
    bf16* __restrict__ Qs, bf16* __restrict__ Ksw, bf16* __restrict__ Vsw,
    float* __restrict__ out, int zbase)
{
    const int z = zbase + blockIdx.z;
    const bf16 *Amat, *Bmat;
    if (z == 0)      { Amat = Wq; Bmat = Xq; }
    else if (z == 1) { Amat = Wk; Bmat = Xk; }
    else if (z == 2) { Amat = Xv; Bmat = Wv; }
    else             { Amat = Wo; Bmat = Ao; }

    // XCD-aware remap (bijective: gy is a multiple of 8 for both launches)
    const int flat = blockIdx.x + 8 * blockIdx.y;
    const int c    = flat & 7;           // XCD (blockid % 8)
    const int j    = flat >> 3;          // position within this XCD's chunk
    const int ft   = j & 7;              // feature tile (8 x 128)
    const int tt   = c * (gridDim.y >> 3) + (j >> 3);  // token tile

    const int m0 = (z == 2 ? tt : ft) * 128;
    const int n0 = (z == 2 ? ft : tt) * BN;

    __shared__ __align__(16) bf16 lA[2][128 * 32];
    __shared__ __align__(16) bf16 lB[2][BN * 32];

    const int tid  = threadIdx.x;
    const int w    = tid >> 6;
    const int lane = tid & 63;
    const int lm   = lane & 15;
    const int g    = lane >> 4;
    const int wm   = (w & 1) * 64;
    const int wn   = (w >> 1) * (BN / 2);
    constexpr int NT = BN / 32;
    constexpr int T  = (128 + BN) / 64;

    f32x4 acc[4][NT] = {};

    for (int kb2 = 0; kb2 < 16; kb2++) {
        __syncthreads();
#pragma unroll
        for (int st = 0; st < 2; st++) {
            int kb = kb2 * 2 + st;
#pragma unroll
            for (int t = 0; t < T; t++) {
                int s   = (t * 4 + w) * 64 + lane;
                int row = s >> 2;
                int gs  = s & 3;
                int gg  = gs ^ ((row >> 1) & 3);
                if (row < 128)
                    async_load16(Amat + (size_t)(m0 + row) * 1024 + kb * 32 + gg * 8,
                                 lA[st] + s * 8);
                else
                    async_load16(Bmat + (size_t)(n0 + row - 128) * 1024 + kb * 32 + gg * 8,
                                 lB[st] + (s - 512) * 8);
            }
        }
        __syncthreads();

#pragma unroll
        for (int st = 0; st < 2; st++) {
            bf16x8 af[4], bfr[NT];
#pragma unroll
            for (int mt = 0; mt < 4; mt++) {
                int row = wm + mt * 16 + lm;
                af[mt] = *(const bf16x8*)(lA[st] + row * 32 + ((g ^ ((row >> 1) & 3)) << 3));
            }
#pragma unroll
            for (int nt = 0; nt < NT; nt++) {
                int row = wn + nt * 16 + lm;
                bfr[nt] = *(const bf16x8*)(lB[st] + row * 32 + ((g ^ ((row >> 1) & 3)) << 3));
            }
#pragma unroll
            for (int mt = 0; mt < 4; mt++)
#pragma unroll
                for (int nt = 0; nt < NT; nt++)
                    acc[mt][nt] = MFMA_BF16(af[mt], bfr[nt], acc[mt][nt]);
        }
    }

    if (z == 3) {
#pragma unroll
        for (int mt = 0; mt < 4; mt++) {
            int mb = m0 + wm + mt * 16 + g * 4;
            f32x4 bov = *(const f32x4*)(bo + mb);
#pragma unroll
            for (int nt = 0; nt < NT; nt++) {
                int n = n0 + wn + nt * 16 + lm;
                f32x4 val;
#pragma unroll
                for (int r = 0; r < 4; r++) val[r] = acc[mt][nt][r] + bov[r];
                *(f32x4*)(out + (size_t)n * 1024 + mb) = val;
            }
        }
    } else if (z == 2) {
#pragma unroll
        for (int mt = 0; mt < 4; mt++) {
            int mb   = m0 + wm + mt * 16 + g * 4;
            int b    = mb >> 11;
            int lpos = mb & 2047;
            int kb2  = lpos >> 6, kc = (lpos >> 5) & 1, gv = (lpos >> 3) & 3, j0 = lpos & 7;
#pragma unroll
            for (int nt = 0; nt < NT; nt++) {
                int n = n0 + wn + nt * 16 + lm;
                int h = n >> 6, mt2 = (n >> 4) & 3, lmv = n & 15;
                bf16x4 ov;
#pragma unroll
                for (int r = 0; r < 4; r++) ov[r] = (bf16)acc[mt][nt][r];
                *(bf16x4*)(Vsw + (size_t)(b * 16 + h) * 131072 +
                           (size_t)((kb2 * 8 + mt2 * 2 + kc) * 64 + gv * 16 + lmv) * 8 + j0) = ov;
            }
        }
    } else if (z == 1) {
#pragma unroll
        for (int mt = 0; mt < 4; mt++) {
            int mb = m0 + wm + mt * 16 + g * 4;
            int h  = mb >> 6;
            int f  = (mb >> 5) & 1, gk = (mb >> 3) & 3, j0 = mb & 7;
#pragma unroll
            for (int nt = 0; nt < NT; nt++) {
                int n    = n0 + wn + nt * 16 + lm;
                int b    = n >> 11;
                int lpos = n & 2047;
                int kb2  = lpos >> 6;
                int rem  = lpos & 63;
                int cc   = ((rem >> 4) & 2) | ((rem >> 2) & 1);
                int lmk  = ((rem >> 1) & 12) | (rem & 3);
                bf16x4 ov;
#pragma unroll
                for (int r = 0; r < 4; r++) ov[r] = (bf16)acc[mt][nt][r];
                *(bf16x4*)(Ksw + (size_t)(b * 16 + h) * 131072 +
                           (size_t)((kb2 * 8 + cc * 2 + f) * 64 + gk * 16 + lmk) * 8 + j0) = ov;
            }
        }
    } else {
        const float qscale = 0.18033688011112042f;  // 1/8 * log2(e)
#pragma unroll
        for (int mt = 0; mt < 4; mt++) {
            int mb  = m0 + wm + mt * 16 + g * 4;
            int h   = mb >> 6;
            int dd0 = mb & 63;
            f32x4 bqv = *(const f32x4*)(bq + mb);
#pragma unroll
            for (int nt = 0; nt < NT; nt++) {
                int n    = n0 + wn + nt * 16 + lm;
                int b    = n >> 11;
                int lpos = n & 2047;
                bf16x4 ov;
#pragma unroll
                for (int r = 0; r < 4; r++)
                    ov[r] = (bf16)((acc[mt][nt][r] + bqv[r]) * qscale);
                *(bf16x4*)(Qs + (size_t)((b * 16 + h) * 2048 + lpos) * 64 + dd0) = ov;
            }
        }
    }
}

// ---------------------------------------------------------------------------
// Flash attention v10 = v9 (K-split, 8 waves, register-direct) + MFMA
// DENOMINATOR. Calibrated model (v8/v9): VALU is the bound pipe (~1742
// cyc/wave-iter vs MFMA ~998); v9 overlaps 2 waves/SIMD so the floor is
// VALU demand (~23 us). v10 moves the softmax-denominator off the VALU:
// a PV-shaped MFMA with A = all-ones computes exact column sums of P,
//   ol[qi] = MFMA(ones, pb[qi][kc], ol[qi])   (8 MFMA/iter, unbound pipe)
// replacing ~64 VALU adds/iter AND the two end-of-loop shuffles (every lane
// ends holding the full sum for its q-column, replicated over r and g).
// Denominator now sums bf16(p) -- consistent with the PV numerator which
// already uses bf16(p); relative shift ~4e-5, inside tolerance.
// K-split combine: upper waves park lsum in psum's pad column (col 64).
__global__ __launch_bounds__(512, 2) void attn_kernel(
    const bf16* __restrict__ Qs, const bf16* __restrict__ Ksw,
    const bf16* __restrict__ Vsw, bf16* __restrict__ attn)
{
    const int tid  = threadIdx.x;
    const int w    = tid >> 6;        // 0..7
    const int wq   = w & 3;           // q sub-chunk
    const int wk   = w >> 2;          // k half
    const int lane = tid & 63;
    const int lm   = lane & 15;
    const int g    = lane >> 4;
    const int i    = blockIdx.x;      // 256 blocks
    const int bh   = ((i & 7) << 2) | ((i >> 3) & 3);  // 4 heads per XCD
    const int q0   = (i >> 5) * 256 + wq * 64;         // 64 q-rows per wave

    const bf16* Qh = Qs  + (size_t)bh * 131072;
    const bf16* Kh = Ksw + (size_t)bh * 131072 + (size_t)wk * 65536;  // k-half base
    const bf16* Vh = Vsw + (size_t)bh * 131072 + (size_t)wk * 65536;

    // psum: 4 x 64 x 68 f32 (cols 0..63 = partial O, col 64 = partial lsum)
    // ost: 4 waves x 64 x 72 bf16. Total ~104 KB -> 1 block/CU.
    __shared__ __align__(16) float psum[4][64][68];
    __shared__ __align__(16) bf16 ost[4][64 * 72];

    // Q fragments (B operand): lane lm = q-row, k(=d) = f*32 + g*8 + j
    bf16x8 qf[4][2];
#pragma unroll
    for (int qi = 0; qi < 4; qi++)
#pragma unroll
        for (int f = 0; f < 2; f++)
            qf[qi][f] = *(const bf16x8*)(Qh + (size_t)(q0 + qi * 16 + lm) * 64 + f * 32 + g * 8);

    const f32x4 fzero = {0.0f, 0.0f, 0.0f, 0.0f};
    f32x4 o[4][4] = {};
    f32x4 ol[4] = {};                 // denominator accumulators (ones-row MFMA)
    const bf16x8 ones = {(bf16)1.0f, (bf16)1.0f, (bf16)1.0f, (bf16)1.0f,
                         (bf16)1.0f, (bf16)1.0f, (bf16)1.0f, (bf16)1.0f};

    // prologue: stripe-0 (of this k-half) fragments into registers
    bf16x8 kf[8], vf[8];
#pragma unroll
    for (int t = 0; t < 8; t++)
        kf[t] = *(const bf16x8*)(Kh + ((size_t)t * 64 + lane) * 8);
#pragma unroll
    for (int t = 0; t < 8; t++)
        vf[t] = *(const bf16x8*)(Vh + ((size_t)t * 64 + lane) * 8);

    for (int kb = 0; kb < 16; kb++) {
        // next-stripe base (clamped: last iteration re-reads stripe 15, unused)
        const int kn = (kb < 15) ? kb + 1 : 15;
        const bf16* Kn = Kh + (size_t)kn * 4096;
        const bf16* Vn = Vh + (size_t)kn * 4096;

        // QK^T + softmax per fragment (4 independent chains -> ILP):
        // s[c][r] = S at k = 32*(c>>1) + 8g + 4*(c&1) + r, q = lm
        bf16x8 pb[4][2];
        __builtin_amdgcn_s_setprio(1);
#pragma unroll
        for (int qi = 0; qi < 4; qi++) {
            f32x4 s[4];
#pragma unroll
            for (int c = 0; c < 4; c++) {
                s[c] = MFMA_BF16(kf[2 * c],     qf[qi][0], fzero);
                s[c] = MFMA_BF16(kf[2 * c + 1], qf[qi][1], s[c]);
            }
            // flat p[]: index kc*8 + j, j 0..3 <- s[2kc][j], j 4..7 <- s[2kc+1][j-4]
            float p[16];
#pragma unroll
            for (int c = 0; c < 4; c++)
#pragma unroll
                for (int r = 0; r < 4; r++)
                    p[(c >> 1) * 8 + (c & 1) * 4 + r] = __builtin_amdgcn_exp2f(s[c][r]);
#pragma unroll
            for (int kc = 0; kc < 2; kc++)
#pragma unroll
                for (int jj = 0; jj < 8; jj++)     // adjacent writes -> cvt_pk
                    pb[qi][kc][jj] = (bf16)p[kc * 8 + jj];
        }
        __builtin_amdgcn_s_setprio(0);

        // reload kf with next stripe -- latency hides under PV (40 MFMAs)
#pragma unroll
        for (int t = 0; t < 8; t++)
            kf[t] = *(const bf16x8*)(Kn + ((size_t)t * 64 + lane) * 8);

        // O^T += V^T P (shared vf fragment feeds all 4 q-fragments);
        // denominator rides the matrix pipe: ones-row MFMA sums P columns.
        __builtin_amdgcn_s_setprio(1);
#pragma unroll
        for (int kc = 0; kc < 2; kc++) {
#pragma unroll
            for (int mt = 0; mt < 4; mt++) {
                bf16x8 vfv = vf[mt * 2 + kc];
#pragma unroll
                for (int qi = 0; qi < 4; qi++)
                    o[qi][mt] = MFMA_BF16(vfv, pb[qi][kc], o[qi][mt]);
            }
#pragma unroll
            for (int qi = 0; qi < 4; qi++)
                ol[qi] = MFMA_BF16(ones, pb[qi][kc], ol[qi]);
        }
        __builtin_amdgcn_s_setprio(0);

        // reload vf with next stripe -- hides under next QK^T + softmax
#pragma unroll
        for (int t = 0; t < 8; t++)
            vf[t] = *(const bf16x8*)(Vn + ((size_t)t * 64 + lane) * 8);
    }

    // ol[qi][r] now holds sum_k P[q=qi*16+lm, k] over this k-half,
    // replicated across r and across g -- no shuffles needed.

    // k-split combine: waves 4-7 park partials, waves 0-3 add + finish
    if (w >= 4) {
#pragma unroll
        for (int qi = 0; qi < 4; qi++) {
#pragma unroll
            for (int mt = 0; mt < 4; mt++)
                *(f32x4*)(&psum[wq][qi * 16 + lm][mt * 16 + g * 4]) = o[qi][mt];
            if (g == 0)
                psum[wq][qi * 16 + lm][64] = ol[qi][0];
        }
    }
    __syncthreads();
    if (w < 4) {
        const int b = bh >> 4, h = bh & 15;
        bf16* ostw = ost[wq];
#pragma unroll
        for (int qi = 0; qi < 4; qi++) {
            float tot = ol[qi][0] + psum[wq][qi * 16 + lm][64];
            float inv = 1.0f / tot;
#pragma unroll
            for (int mt = 0; mt < 4; mt++) {
                f32x4 ps = *(const f32x4*)(&psum[wq][qi * 16 + lm][mt * 16 + g * 4]);
                bf16x4 ov;
#pragma unroll
                for (int r = 0; r < 4; r++)
                    ov[r] = (bf16)((o[qi][mt][r] + ps[r]) * inv);
                *(bf16x4*)(ostw + (qi * 16 + lm) * 72 + mt * 16 + g * 4) = ov;
            }
        }
        __builtin_amdgcn_s_waitcnt(0);  // lgkmcnt(0) before re-reading own region
#pragma unroll
        for (int it = 0; it < 8; it++) {
            int cc = it * 64 + lane;
            int q  = cc >> 3, ch = cc & 7;
            bf16x8 t = *(const bf16x8*)(ostw + q * 72 + ch * 8);
            *(bf16x8*)(attn + (size_t)(b * 2048 + q0 + q) * 1024 + h * 64 + ch * 8) = t;
        }
    }
}

// ---------------------------------------------------------------------------
extern "C" void kernel_launch(void* const* d_in, const int* in_sizes, int n_in,
                              void* d_out, int out_size, void* d_ws, size_t ws_size,
                              hipStream_t stream) {
    const float* query = (const float*)d_in[0];
    const float* key   = (const float*)d_in[1];
    const float* value = (const float*)d_in[2];
    const float* Wq    = (const float*)d_in[3];
    const float* bq    = (const float*)d_in[4];
    const float* Wk    = (const float*)d_in[5];
    const float* Wv    = (const float*)d_in[6];
    const float* Wo    = (const float*)d_in[7];
    const float* bo    = (const float*)d_in[8];

    char* ws = (char*)d_ws;
    bf16* Xq  = (bf16*)(ws);
    bf16* Xk  = (bf16*)(ws + ((size_t)8  << 20));
    bf16* Xv  = (bf16*)(ws + ((size_t)16 << 20));
    bf16* Wqb = (bf16*)(ws + ((size_t)24 << 20));
    bf16* Wkb = (bf16*)(ws + ((size_t)26 << 20));
    bf16* Wvb = (bf16*)(ws + ((size_t)28 << 20));
    bf16* Wob = (bf16*)(ws + ((size_t)30 << 20));
    bf16* Qs  = (bf16*)(ws + ((size_t)32 << 20));
    bf16* Ksw = (bf16*)(ws + ((size_t)40 << 20));
    bf16* Vsw = (bf16*)(ws + ((size_t)48 << 20));
    bf16* attn = Xq;  // Xq dead after projections

    cvt_bf16_kernel<<<dim3(16384, 1, 1), 256, 0, stream>>>(
        query, key, value, Wq, Wk, Wv, Wo, Xq, Xk, Xv, Wqb, Wkb, Wvb, Wob);

    gemm4_kernel<128><<<dim3(8, 32, 3), 256, 0, stream>>>(
        Xq, Xk, Xv, attn, Wqb, Wkb, Wvb, Wob, bq, bo, Qs, Ksw, Vsw, (float*)d_out, 0);

    attn_kernel<<<dim3(256, 1, 1), 512, 0, stream>>>(Qs, Ksw, Vsw, attn);

    gemm4_kernel<64><<<dim3(8, 64, 1), 256, 0, stream>>>(
        Xq, Xk, Xv, attn, Wqb, Wkb, Wvb, Wob, bq, bo, Qs, Ksw, Vsw, (float*)d_out, 3);
}